// Round 5
// baseline (350.607 us; speedup 1.0000x reference)
//
#include <hip/hip_runtime.h>
#include <hip/hip_fp16.h>
#include <cstdint>
#include <cstddef>
#include <cstring>

// ---------------- bf16 pack/unpack helpers (RNE) ----------------

__device__ inline unsigned pack_bf16x2(float a, float b) {
    unsigned ua = __float_as_uint(a);
    unsigned ub = __float_as_uint(b);
    ua += 0x7fffu + ((ua >> 16) & 1u);
    ub += 0x7fffu + ((ub >> 16) & 1u);
    return (ua >> 16) | (ub & 0xffff0000u);
}
__device__ inline unsigned short bf16_rne(float v) {
    unsigned u = __float_as_uint(v);
    u += 0x7fffu + ((u >> 16) & 1u);
    return (unsigned short)(u >> 16);
}

// ---------------- fp8 (OCP e4m3fn) pack/unpack ----------------

typedef float fv2 __attribute__((ext_vector_type(2)));

template <bool HI>
__device__ inline fv2 fp8_fv2(unsigned u) {
#if __has_builtin(__builtin_amdgcn_cvt_pk_f32_fp8)
    return __builtin_amdgcn_cvt_pk_f32_fp8((int)u, HI);
#else
    unsigned u2 = HI ? (u >> 16) : (u & 0xffffu);
    unsigned w = (u2 & 0xFFu) | ((u2 & 0xFF00u) << 8);
    unsigned hb = ((w & 0x00800080u) << 8) | ((w & 0x007f007fu) << 7);
    __half2 h2;
    memcpy(&h2, &hb, 4);
    float2 f = __half22float2(h2);
    fv2 r;
    r.x = f.x * 256.0f;
    r.y = f.y * 256.0f;
    return r;
#endif
}

// bf16 pair (packed in a uint) -> fv2  (2 bitops, then packed add on use)
__device__ inline fv2 bfpair(unsigned u) {
    union { unsigned q[2]; fv2 f; } t;
    t.q[0] = u << 16;
    t.q[1] = u & 0xffff0000u;
    return t.f;
}

__device__ inline unsigned f32_to_fp8_byte(float v) {
    unsigned short hb = __half_as_ushort(__float2half(v * 0.00390625f));  // v/256
    unsigned t = hb & 0x7fffu;
    t += 0x3fu + ((t >> 7) & 1u);
    return ((hb >> 8) & 0x80u) | (t >> 7);
}

__device__ inline unsigned char f32_to_fp8_b(float v) {
#if __has_builtin(__builtin_amdgcn_cvt_pk_fp8_f32)
    return (unsigned char)(__builtin_amdgcn_cvt_pk_fp8_f32(v, v, 0, false) & 0xff);
#else
    return (unsigned char)f32_to_fp8_byte(v);
#endif
}

typedef int iv4 __attribute__((ext_vector_type(4)));

#define NPART 8

// ---------------- CSR build: hybrid direct-atomic + partitioned fill --------
// R16 restructure. Constraints proven by earlier rounds:
//  - R14: direct global atomicAdd into a 400 KB indeg array is CHEAP (atomics
//    execute in L2, window L2-resident, writeback = 400 KB).
//  - R14/R3 lesson: the col scatter-WRITE must be confined to an L2-sized
//    window per concurrent worker set, else ~16x HBM write amplification.
// So: degree counting needs NO partitioning; only the fill does. The whole
// cntarr LDS-histogram machinery (12.8 MB x3 traffic) is deleted.
//  k_bucket_deg: one edge pass -> direct indeg atomics + partition edges into
//    8 fixed-capacity segments, packed u32 (dl<<SRCB | src, 14+17=31 bits).
//  k_fill3: per-partition chunks; cursor atomics in a 50 KB window, col
//    writes in an ~800 KB window, both L2-resident.

__global__ __launch_bounds__(256) void k_bucket_deg(const int* __restrict__ src,
                                                    const int* __restrict__ dst,
                                                    int* __restrict__ indeg,
                                                    int* __restrict__ cursor8,
                                                    unsigned* __restrict__ pairs,
                                                    int E, int npp, int capE, int srcb) {
    __shared__ int cnt8[NPART], run8[NPART], gbase8[NPART];
    int tid = threadIdx.x;
    int base_e = blockIdx.x * 4096 + tid * 16;
    int nv = min(16, E - base_e);
    if (nv < 0) nv = 0;
    int dv[16], sv[16];
    if (nv == 16) {
        for (int q = 0; q < 4; ++q) {
            iv4 d = *(const iv4*)(dst + base_e + q * 4);
            iv4 s = *(const iv4*)(src + base_e + q * 4);
            dv[q * 4 + 0] = d.x; dv[q * 4 + 1] = d.y; dv[q * 4 + 2] = d.z; dv[q * 4 + 3] = d.w;
            sv[q * 4 + 0] = s.x; sv[q * 4 + 1] = s.y; sv[q * 4 + 2] = s.z; sv[q * 4 + 3] = s.w;
        }
    } else {
        for (int k = 0; k < nv; ++k) { dv[k] = dst[base_e + k]; sv[k] = src[base_e + k]; }
    }
    if (tid < NPART) { cnt8[tid] = 0; run8[tid] = 0; }
    __syncthreads();
    for (int k = 0; k < nv; ++k) {
        int d = dv[k];
        atomicAdd(&cnt8[(unsigned)d / (unsigned)npp], 1);
        atomicAdd(&indeg[d], 1);   // fire-and-forget, 400 KB L2-resident window
    }
    __syncthreads();
    if (tid < NPART)
        gbase8[tid] = atomicAdd(&cursor8[tid], cnt8[tid]) + tid * capE;
    __syncthreads();
    for (int k = 0; k < nv; ++k) {
        int d = dv[k];
        int p = (unsigned)d / (unsigned)npp;
        int r = atomicAdd(&run8[p], 1);
        pairs[gbase8[p] + r] = ((unsigned)(d - p * npp) << srcb) | (unsigned)sv[k];
    }
}

// degree -> dinv + block-local exclusive scan (reads 400 KB indeg directly)
__global__ void k_indeg_scan(const int* __restrict__ indeg,
                             float* __restrict__ dinv,
                             int* __restrict__ row_ptr,
                             int* __restrict__ partials, int n) {
    __shared__ int s[256];
    int t = threadIdx.x;
    int node0 = blockIdx.x * 1024 + t * 4;
    int v0 = 0, v1 = 0, v2 = 0, v3 = 0;
    if (node0 + 3 < n) {
        iv4 v = *(const iv4*)(indeg + node0);
        v0 = v.x; v1 = v.y; v2 = v.z; v3 = v.w;
    } else {
        if (node0 + 0 < n) v0 = indeg[node0 + 0];
        if (node0 + 1 < n) v1 = indeg[node0 + 1];
        if (node0 + 2 < n) v2 = indeg[node0 + 2];
        if (node0 + 3 < n) v3 = indeg[node0 + 3];
    }
    if (node0 + 0 < n) dinv[node0 + 0] = rsqrtf((float)v0 + 1.0f);
    if (node0 + 1 < n) dinv[node0 + 1] = rsqrtf((float)v1 + 1.0f);
    if (node0 + 2 < n) dinv[node0 + 2] = rsqrtf((float)v2 + 1.0f);
    if (node0 + 3 < n) dinv[node0 + 3] = rsqrtf((float)v3 + 1.0f);
    int sum = v0 + v1 + v2 + v3;
    s[t] = sum;
    __syncthreads();
    for (int off = 1; off < 256; off <<= 1) {
        int x = (t >= off) ? s[t - off] : 0;
        __syncthreads();
        s[t] += x;
        __syncthreads();
    }
    int excl = s[t] - sum;
    if ((node0 + 0) < n) row_ptr[node0 + 0] = excl;
    if ((node0 + 1) < n) row_ptr[node0 + 1] = excl + v0;
    if ((node0 + 2) < n) row_ptr[node0 + 2] = excl + v0 + v1;
    if ((node0 + 3) < n) row_ptr[node0 + 3] = excl + v0 + v1 + v2;
    if (t == 255) partials[blockIdx.x] = s[255];
}

__global__ void k_scan_partials(int* __restrict__ partials, int np) {
    __shared__ int s[256];
    int t = threadIdx.x;
    int v = (t < np) ? partials[t] : 0;
    s[t] = v;
    __syncthreads();
    for (int off = 1; off < 256; off <<= 1) {
        int x = (t >= off) ? s[t - off] : 0;
        __syncthreads();
        s[t] += x;
        __syncthreads();
    }
    if (t < np) partials[t] = s[t] - v;
}

// row_ptr fixup + cursor init (cursor aliases the dead indeg array)
__global__ void k_finalize_cur(int* __restrict__ row_ptr,
                               const int* __restrict__ partials,
                               int* __restrict__ cursor, int n, int E) {
    int i = blockIdx.x * blockDim.x + threadIdx.x;
    if (i >= n) return;
    int rp = row_ptr[i] + partials[i >> 10];
    row_ptr[i] = rp;
    cursor[i] = rp;
    if (i == 0) row_ptr[n] = E;
}

__global__ __launch_bounds__(256) void k_fill3(const unsigned* __restrict__ pairs,
                                               const int* __restrict__ cursor8,
                                               int* __restrict__ cursor,
                                               int* __restrict__ col,
                                               int npp, int capE, int srcb) {
    int p = blockIdx.x & (NPART - 1);
    int b = blockIdx.x >> 3;
    int nb = gridDim.x >> 3;
    int sz = cursor8[p];
    int segBase = p * capE;
    int chunk = (sz + nb - 1) / nb;
    int s0 = segBase + b * chunk;
    int s1 = min(segBase + sz, s0 + chunk);
    int lo = p * npp;
    unsigned smask = (1u << srcb) - 1u;
    int i = s0 + threadIdx.x;
    // 4-deep unroll: batch loads, then atomics, then stores (MLP on the
    // atomic-return latency chain)
    for (; i + 768 < s1; i += 1024) {
        unsigned u0 = pairs[i];
        unsigned u1 = pairs[i + 256];
        unsigned u2 = pairs[i + 512];
        unsigned u3 = pairs[i + 768];
        int p0 = atomicAdd(&cursor[lo + (int)(u0 >> srcb)], 1);
        int p1 = atomicAdd(&cursor[lo + (int)(u1 >> srcb)], 1);
        int p2 = atomicAdd(&cursor[lo + (int)(u2 >> srcb)], 1);
        int p3 = atomicAdd(&cursor[lo + (int)(u3 >> srcb)], 1);
        col[p0] = (int)(u0 & smask);
        col[p1] = (int)(u1 & smask);
        col[p2] = (int)(u2 & smask);
        col[p3] = (int)(u3 & smask);
    }
    for (; i < s1; i += 256) {
        unsigned u = pairs[i];
        col[atomicAdd(&cursor[lo + (int)(u >> srcb)], 1)] = (int)(u & smask);
    }
}

// ---------------- MFMA GEMMs ----------------
typedef __attribute__((ext_vector_type(8))) short short8;
typedef __attribute__((ext_vector_type(4))) float f32x4;

union FragU {
    short8 s;
    uint4 u4;
    unsigned u[4];
};

__device__ inline void packW_body(const float* __restrict__ W, unsigned* __restrict__ Bp,
                                  int NOUT, int NT) {
    int nf = 4 * NT * 64;
    for (int fid = threadIdx.x; fid < nf; fid += 256) {
        int q = fid / (NT * 64);
        int rem = fid - q * NT * 64;
        int nt = rem >> 6;
        int lane = rem & 63;
        int k0 = q * 32 + (lane >> 4) * 8;
        int ncol = nt * 16 + (lane & 15);
        unsigned u[4];
        for (int h = 0; h < 4; ++h) {
            float a = W[(k0 + 2 * h) * NOUT + ncol];
            float b = W[(k0 + 2 * h + 1) * NOUT + ncol];
            u[h] = pack_bf16x2(a, b);
        }
        uint4 o = {u[0], u[1], u[2], u[3]};
        *(uint4*)(Bp + (size_t)fid * 4) = o;
    }
}

// both weight packs in one dispatch (block 0 -> W1, block 1 -> W2)
__global__ void k_packW2(const float* __restrict__ W1, unsigned* __restrict__ Bp1,
                         const float* __restrict__ W2, unsigned* __restrict__ Bp2) {
    if (blockIdx.x == 0) packW_body(W1, Bp1, 128, 8);
    else                 packW_body(W2, Bp2, 64, 4);
}

__global__ __launch_bounds__(256) void k_gemm128_mfma(const float* __restrict__ X,
                                                      const unsigned* __restrict__ Bp,
                                                      const float* __restrict__ dinv,
                                                      unsigned char* __restrict__ H8,
                                                      int n) {
    int w = threadIdx.x >> 6;
    int lane = threadIdx.x & 63;
    int quad = lane >> 4;
    int lrow = lane & 15;
    int row0 = blockIdx.x * 64 + w * 16;
    int rowA = min(row0 + lrow, n - 1);

    f32x4 acc[8];
    for (int nt = 0; nt < 8; ++nt) acc[nt] = (f32x4){0.f, 0.f, 0.f, 0.f};

    for (int q = 0; q < 4; ++q) {
        const float* xp = X + (size_t)rowA * 128 + q * 32 + quad * 8;
        float4 x0 = *(const float4*)xp;
        float4 x1 = *(const float4*)(xp + 4);
        FragU a;
        a.u[0] = pack_bf16x2(x0.x, x0.y);
        a.u[1] = pack_bf16x2(x0.z, x0.w);
        a.u[2] = pack_bf16x2(x1.x, x1.y);
        a.u[3] = pack_bf16x2(x1.z, x1.w);
        for (int nt = 0; nt < 8; ++nt) {
            FragU b;
            b.u4 = *(const uint4*)(Bp + ((size_t)(q * 8 + nt) * 64 + lane) * 4);
            acc[nt] = __builtin_amdgcn_mfma_f32_16x16x32_bf16(a.s, b.s, acc[nt], 0, 0, 0);
        }
    }

    int rbase = row0 + quad * 4;
    float dv[4];
    if (rbase + 3 < n) {
        float4 d4 = *(const float4*)(dinv + rbase);
        dv[0] = d4.x; dv[1] = d4.y; dv[2] = d4.z; dv[3] = d4.w;
    } else {
        for (int r = 0; r < 4; ++r) dv[r] = dinv[min(rbase + r, n - 1)];
    }
    for (int nt = 0; nt < 8; ++nt) {
        for (int r = 0; r < 4; ++r) {
            int row = rbase + r;
            if (row < n)
                H8[(size_t)row * 128 + nt * 16 + lrow] = f32_to_fp8_b(dv[r] * acc[nt][r]);
        }
    }
}

__global__ __launch_bounds__(256) void k_gemm64_mfma(const unsigned* __restrict__ Xb,
                                                     const unsigned* __restrict__ Bp,
                                                     const float* __restrict__ dinv,
                                                     unsigned short* __restrict__ H16,
                                                     int n) {
    int w = threadIdx.x >> 6;
    int lane = threadIdx.x & 63;
    int quad = lane >> 4;
    int lrow = lane & 15;
    int row0 = blockIdx.x * 64 + w * 16;
    int rowA = min(row0 + lrow, n - 1);

    f32x4 acc[4];
    for (int nt = 0; nt < 4; ++nt) acc[nt] = (f32x4){0.f, 0.f, 0.f, 0.f};

    for (int q = 0; q < 4; ++q) {
        FragU a;
        a.u4 = *(const uint4*)(Xb + (size_t)rowA * 64 + q * 16 + quad * 4);
        for (int nt = 0; nt < 4; ++nt) {
            FragU b;
            b.u4 = *(const uint4*)(Bp + ((size_t)(q * 4 + nt) * 64 + lane) * 4);
            acc[nt] = __builtin_amdgcn_mfma_f32_16x16x32_bf16(a.s, b.s, acc[nt], 0, 0, 0);
        }
    }

    int rbase = row0 + quad * 4;
    float dv[4];
    if (rbase + 3 < n) {
        float4 d4 = *(const float4*)(dinv + rbase);
        dv[0] = d4.x; dv[1] = d4.y; dv[2] = d4.z; dv[3] = d4.w;
    } else {
        for (int r = 0; r < 4; ++r) dv[r] = dinv[min(rbase + r, n - 1)];
    }
    for (int nt = 0; nt < 4; ++nt) {
        for (int r = 0; r < 4; ++r) {
            int row = rbase + r;
            if (row < n)
                H16[(size_t)row * 64 + nt * 16 + lrow] = bf16_rne(dv[r] * acc[nt][r]);
        }
    }
}

// ---------------- Pull-mode aggregation: quarter-wave PER NODE ----------------
// R13-proven structure: each 16-lane quarter owns ONE node; lane l owns bytes
// 8l..8l+7 of the node's 128 B feature row. No cross-lane reduce in layer 1;
// col indices are quarter-uniform scalar loads; 8-edge unroll keeps 8 loads
// in flight per lane.

// Layer 1: hs rows = 16 uint2 (128 fp8). Lane owns fp8 cols 8l..8l+7.
__global__ __launch_bounds__(256) void k_agg_relu(const unsigned* __restrict__ hs,
                                                  const float* __restrict__ dinv,
                                                  const int* __restrict__ row_ptr,
                                                  const int* __restrict__ col,
                                                  const float* __restrict__ bias,
                                                  unsigned* __restrict__ out, int n) {
    int node = blockIdx.x * 16 + (threadIdx.x >> 4);
    if (node >= n) return;
    int l = threadIdx.x & 15;
    const uint2* hrow = (const uint2*)hs;
    fv2 a0 = {0.f, 0.f}, a1 = {0.f, 0.f}, a2 = {0.f, 0.f}, a3 = {0.f, 0.f};
    {   // self term
        uint2 u = hrow[(size_t)node * 16 + l];
        a0 += fp8_fv2<false>(u.x); a1 += fp8_fv2<true>(u.x);
        a2 += fp8_fv2<false>(u.y); a3 += fp8_fv2<true>(u.y);
    }
    int k = row_ptr[node], p1 = row_ptr[node + 1];
    for (; k + 8 <= p1; k += 8) {  // 8 edges/quarter, 8 loads in flight/lane
        int cA = col[k + 0], cB = col[k + 1], cC = col[k + 2], cD = col[k + 3];
        int cE = col[k + 4], cF = col[k + 5], cG = col[k + 6], cH = col[k + 7];
        uint2 uA = hrow[(size_t)cA * 16 + l];
        uint2 uB = hrow[(size_t)cB * 16 + l];
        uint2 uC = hrow[(size_t)cC * 16 + l];
        uint2 uD = hrow[(size_t)cD * 16 + l];
        uint2 uE = hrow[(size_t)cE * 16 + l];
        uint2 uF = hrow[(size_t)cF * 16 + l];
        uint2 uG = hrow[(size_t)cG * 16 + l];
        uint2 uH = hrow[(size_t)cH * 16 + l];
        a0 += fp8_fv2<false>(uA.x); a1 += fp8_fv2<true>(uA.x);
        a2 += fp8_fv2<false>(uA.y); a3 += fp8_fv2<true>(uA.y);
        a0 += fp8_fv2<false>(uB.x); a1 += fp8_fv2<true>(uB.x);
        a2 += fp8_fv2<false>(uB.y); a3 += fp8_fv2<true>(uB.y);
        a0 += fp8_fv2<false>(uC.x); a1 += fp8_fv2<true>(uC.x);
        a2 += fp8_fv2<false>(uC.y); a3 += fp8_fv2<true>(uC.y);
        a0 += fp8_fv2<false>(uD.x); a1 += fp8_fv2<true>(uD.x);
        a2 += fp8_fv2<false>(uD.y); a3 += fp8_fv2<true>(uD.y);
        a0 += fp8_fv2<false>(uE.x); a1 += fp8_fv2<true>(uE.x);
        a2 += fp8_fv2<false>(uE.y); a3 += fp8_fv2<true>(uE.y);
        a0 += fp8_fv2<false>(uF.x); a1 += fp8_fv2<true>(uF.x);
        a2 += fp8_fv2<false>(uF.y); a3 += fp8_fv2<true>(uF.y);
        a0 += fp8_fv2<false>(uG.x); a1 += fp8_fv2<true>(uG.x);
        a2 += fp8_fv2<false>(uG.y); a3 += fp8_fv2<true>(uG.y);
        a0 += fp8_fv2<false>(uH.x); a1 += fp8_fv2<true>(uH.x);
        a2 += fp8_fv2<false>(uH.y); a3 += fp8_fv2<true>(uH.y);
    }
    for (; k + 4 <= p1; k += 4) {
        int cA = col[k + 0], cB = col[k + 1], cC = col[k + 2], cD = col[k + 3];
        uint2 uA = hrow[(size_t)cA * 16 + l];
        uint2 uB = hrow[(size_t)cB * 16 + l];
        uint2 uC = hrow[(size_t)cC * 16 + l];
        uint2 uD = hrow[(size_t)cD * 16 + l];
        a0 += fp8_fv2<false>(uA.x); a1 += fp8_fv2<true>(uA.x);
        a2 += fp8_fv2<false>(uA.y); a3 += fp8_fv2<true>(uA.y);
        a0 += fp8_fv2<false>(uB.x); a1 += fp8_fv2<true>(uB.x);
        a2 += fp8_fv2<false>(uB.y); a3 += fp8_fv2<true>(uB.y);
        a0 += fp8_fv2<false>(uC.x); a1 += fp8_fv2<true>(uC.x);
        a2 += fp8_fv2<false>(uC.y); a3 += fp8_fv2<true>(uC.y);
        a0 += fp8_fv2<false>(uD.x); a1 += fp8_fv2<true>(uD.x);
        a2 += fp8_fv2<false>(uD.y); a3 += fp8_fv2<true>(uD.y);
    }
    for (; k < p1; ++k) {
        int j = col[k];
        uint2 u = hrow[(size_t)j * 16 + l];
        a0 += fp8_fv2<false>(u.x); a1 += fp8_fv2<true>(u.x);
        a2 += fp8_fv2<false>(u.y); a3 += fp8_fv2<true>(u.y);
    }
    // epilogue: every lane finalizes its own 8 columns (4 nodes per wave)
    float di = dinv[node];
    float4 b4a = *(const float4*)(bias + 8 * l);
    float4 b4b = *(const float4*)(bias + 8 * l + 4);
    float v0 = fmaf(di, a0.x, b4a.x);
    float v1 = fmaf(di, a0.y, b4a.y);
    float v2 = fmaf(di, a1.x, b4a.z);
    float v3 = fmaf(di, a1.y, b4a.w);
    float v4 = fmaf(di, a2.x, b4b.x);
    float v5 = fmaf(di, a2.y, b4b.y);
    float v6 = fmaf(di, a3.x, b4b.z);
    float v7 = fmaf(di, a3.y, b4b.w);
    v0 = v0 > 0.f ? v0 : 0.f;
    v1 = v1 > 0.f ? v1 : 0.f;
    v2 = v2 > 0.f ? v2 : 0.f;
    v3 = v3 > 0.f ? v3 : 0.f;
    v4 = v4 > 0.f ? v4 : 0.f;
    v5 = v5 > 0.f ? v5 : 0.f;
    v6 = v6 > 0.f ? v6 : 0.f;
    v7 = v7 > 0.f ? v7 : 0.f;
    uint4 o = {pack_bf16x2(v0, v1), pack_bf16x2(v2, v3),
               pack_bf16x2(v4, v5), pack_bf16x2(v6, v7)};
    *(uint4*)(out + (size_t)node * 64 + 4 * l) = o;
}

// Layer 2: hs rows = 16 uint2 (64 bf16). Lane owns bf16 cols 4l..4l+3.
// Fused log_softmax: 16-lane reduce (xor offsets 1..8 stay inside the quarter).
__global__ __launch_bounds__(256) void k_agg_lsm(const unsigned* __restrict__ hs,
                                                 const float* __restrict__ dinv,
                                                 const int* __restrict__ row_ptr,
                                                 const int* __restrict__ col,
                                                 const float* __restrict__ bias,
                                                 float* __restrict__ out, int n) {
    int node = blockIdx.x * 16 + (threadIdx.x >> 4);
    if (node >= n) return;
    int l = threadIdx.x & 15;
    const uint2* hrow = (const uint2*)hs;
    fv2 aX = {0.f, 0.f}, aY = {0.f, 0.f};
    {   // self term
        uint2 u = hrow[(size_t)node * 16 + l];
        aX += bfpair(u.x);
        aY += bfpair(u.y);
    }
    int k = row_ptr[node], p1 = row_ptr[node + 1];
    for (; k + 8 <= p1; k += 8) {
        int cA = col[k + 0], cB = col[k + 1], cC = col[k + 2], cD = col[k + 3];
        int cE = col[k + 4], cF = col[k + 5], cG = col[k + 6], cH = col[k + 7];
        uint2 uA = hrow[(size_t)cA * 16 + l];
        uint2 uB = hrow[(size_t)cB * 16 + l];
        uint2 uC = hrow[(size_t)cC * 16 + l];
        uint2 uD = hrow[(size_t)cD * 16 + l];
        uint2 uE = hrow[(size_t)cE * 16 + l];
        uint2 uF = hrow[(size_t)cF * 16 + l];
        uint2 uG = hrow[(size_t)cG * 16 + l];
        uint2 uH = hrow[(size_t)cH * 16 + l];
        aX += bfpair(uA.x); aY += bfpair(uA.y);
        aX += bfpair(uB.x); aY += bfpair(uB.y);
        aX += bfpair(uC.x); aY += bfpair(uC.y);
        aX += bfpair(uD.x); aY += bfpair(uD.y);
        aX += bfpair(uE.x); aY += bfpair(uE.y);
        aX += bfpair(uF.x); aY += bfpair(uF.y);
        aX += bfpair(uG.x); aY += bfpair(uG.y);
        aX += bfpair(uH.x); aY += bfpair(uH.y);
    }
    for (; k + 4 <= p1; k += 4) {
        int cA = col[k + 0], cB = col[k + 1], cC = col[k + 2], cD = col[k + 3];
        uint2 uA = hrow[(size_t)cA * 16 + l];
        uint2 uB = hrow[(size_t)cB * 16 + l];
        uint2 uC = hrow[(size_t)cC * 16 + l];
        uint2 uD = hrow[(size_t)cD * 16 + l];
        aX += bfpair(uA.x); aY += bfpair(uA.y);
        aX += bfpair(uB.x); aY += bfpair(uB.y);
        aX += bfpair(uC.x); aY += bfpair(uC.y);
        aX += bfpair(uD.x); aY += bfpair(uD.y);
    }
    for (; k < p1; ++k) {
        int j = col[k];
        uint2 u = hrow[(size_t)j * 16 + l];
        aX += bfpair(u.x); aY += bfpair(u.y);
    }
    float di = dinv[node];
    float4 b4 = *(const float4*)(bias + 4 * l);
    float v0 = fmaf(di, aX.x, b4.x);
    float v1 = fmaf(di, aX.y, b4.y);
    float v2 = fmaf(di, aY.x, b4.z);
    float v3 = fmaf(di, aY.y, b4.w);
    float m = fmaxf(fmaxf(v0, v1), fmaxf(v2, v3));
    for (int off = 8; off; off >>= 1) m = fmaxf(m, __shfl_xor(m, off));
    float s = __expf(v0 - m) + __expf(v1 - m) + __expf(v2 - m) + __expf(v3 - m);
    for (int off = 8; off; off >>= 1) s += __shfl_xor(s, off);
    float ls = __logf(s);
    float4 o = {v0 - m - ls, v1 - m - ls, v2 - m - ls, v3 - m - ls};
    *(float4*)(out + (size_t)node * 64 + 4 * l) = o;
}

// ---------------- launcher ----------------

extern "C" void kernel_launch(void* const* d_in, const int* in_sizes, int n_in,
                              void* d_out, int out_size, void* d_ws, size_t ws_size,
                              hipStream_t stream) {
    const float* x  = (const float*)d_in[0];
    const int*   ei = (const int*)d_in[1];
    const float* W1 = (const float*)d_in[2];
    const float* b1 = (const float*)d_in[3];
    const float* W2 = (const float*)d_in[4];
    const float* b2 = (const float*)d_in[5];
    float* out = (float*)d_out;

    const int N = in_sizes[0] / 128;   // 100000
    const int E = in_sizes[1] / 2;     // 1600000
    const int* src = ei;
    const int* dst = ei + E;
    const int npp = (N + NPART - 1) / NPART;     // 12500
    const int capE = (E + NPART - 1) / NPART + 32768;  // segment capacity + slack
    int srcb = 1;
    while ((1 << srcb) < N) ++srcb;              // 17 for N=100000 (dl<<17 fits: npp<2^15)

    char* w = (char*)d_ws;
    size_t off = 0;
    auto alloc = [&](size_t bytes) -> void* {
        void* p = w + off;
        off += (bytes + 255) & ~(size_t)255;
        return p;
    };
    int*      indeg    = (int*)alloc((size_t)(N + 8) * 4);      // degree -> cursor; +8 = cursor8
    int*      row_ptr  = (int*)alloc((size_t)(N + 1) * 4);
    int*      colarr   = (int*)alloc((size_t)E * 4);
    int*      partials = (int*)alloc(256 * 4);
    float*    dinv     = (float*)alloc((size_t)N * 4);
    unsigned* h1f8     = (unsigned*)alloc((size_t)N * 32 * 4);  // fp8 X@W1 scaled
    unsigned* a1b      = (unsigned*)alloc((size_t)N * 64 * 4);  // bf16 relu out
    unsigned* h2b      = (unsigned*)alloc((size_t)N * 32 * 4);  // bf16 a1@W2 scaled
    unsigned* Bp1      = (unsigned*)alloc(4 * 8 * 64 * 16);     // W1 frag stream 32KB
    unsigned* Bp2      = (unsigned*)alloc(4 * 4 * 64 * 16);     // W2 frag stream 16KB
    unsigned* pairsU   = (unsigned*)a1b;  // 8*capE*4 ~ 7.5MB, dead before agg_relu
    int*      cursor8  = indeg + N;
    (void)ws_size; (void)n_in; (void)out_size;

    int nscan = (N + 1023) / 1024;
    int nA3 = (E + 4095) / 4096;
    int ngemm = (N + 63) / 64;

    hipMemsetAsync(indeg, 0, (size_t)(N + 8) * 4, stream);
    k_packW2<<<2, 256, 0, stream>>>(W1, Bp1, W2, Bp2);
    k_bucket_deg<<<nA3, 256, 0, stream>>>(src, dst, indeg, cursor8, pairsU,
                                          E, npp, capE, srcb);
    k_indeg_scan<<<nscan, 256, 0, stream>>>(indeg, dinv, row_ptr, partials, N);
    k_scan_partials<<<1, 256, 0, stream>>>(partials, nscan);
    k_finalize_cur<<<(N + 255) / 256, 256, 0, stream>>>(row_ptr, partials, indeg, N, E);
    k_fill3<<<256, 256, 0, stream>>>(pairsU, cursor8, indeg, colarr, npp, capE, srcb);

    k_gemm128_mfma<<<ngemm, 256, 0, stream>>>(x, Bp1, dinv, (unsigned char*)h1f8, N);
    k_agg_relu<<<(N + 15) / 16, 256, 0, stream>>>(h1f8, dinv, row_ptr, colarr, b1, a1b, N);
    k_gemm64_mfma<<<ngemm, 256, 0, stream>>>(a1b, Bp2, dinv, (unsigned short*)h2b, N);
    k_agg_lsm<<<(N + 15) / 16, 256, 0, stream>>>(h2b, dinv, row_ptr, colarr, b2, out, N);
}

// Round 6
// 269.344 us; speedup vs baseline: 1.3017x; 1.3017x over previous
//
#include <hip/hip_runtime.h>
#include <hip/hip_fp16.h>
#include <cstdint>
#include <cstddef>
#include <cstring>

// ---------------- bf16 pack/unpack helpers (RNE) ----------------

__device__ inline unsigned pack_bf16x2(float a, float b) {
    unsigned ua = __float_as_uint(a);
    unsigned ub = __float_as_uint(b);
    ua += 0x7fffu + ((ua >> 16) & 1u);
    ub += 0x7fffu + ((ub >> 16) & 1u);
    return (ua >> 16) | (ub & 0xffff0000u);
}
__device__ inline unsigned short bf16_rne(float v) {
    unsigned u = __float_as_uint(v);
    u += 0x7fffu + ((u >> 16) & 1u);
    return (unsigned short)(u >> 16);
}

// ---------------- fp8 (OCP e4m3fn) pack/unpack ----------------

typedef float fv2 __attribute__((ext_vector_type(2)));

template <bool HI>
__device__ inline fv2 fp8_fv2(unsigned u) {
#if __has_builtin(__builtin_amdgcn_cvt_pk_f32_fp8)
    return __builtin_amdgcn_cvt_pk_f32_fp8((int)u, HI);
#else
    unsigned u2 = HI ? (u >> 16) : (u & 0xffffu);
    unsigned w = (u2 & 0xFFu) | ((u2 & 0xFF00u) << 8);
    unsigned hb = ((w & 0x00800080u) << 8) | ((w & 0x007f007fu) << 7);
    __half2 h2;
    memcpy(&h2, &hb, 4);
    float2 f = __half22float2(h2);
    fv2 r;
    r.x = f.x * 256.0f;
    r.y = f.y * 256.0f;
    return r;
#endif
}

// bf16 pair (packed in a uint) -> fv2  (2 bitops, then packed add on use)
__device__ inline fv2 bfpair(unsigned u) {
    union { unsigned q[2]; fv2 f; } t;
    t.q[0] = u << 16;
    t.q[1] = u & 0xffff0000u;
    return t.f;
}

__device__ inline unsigned f32_to_fp8_byte(float v) {
    unsigned short hb = __half_as_ushort(__float2half(v * 0.00390625f));  // v/256
    unsigned t = hb & 0x7fffu;
    t += 0x3fu + ((t >> 7) & 1u);
    return ((hb >> 8) & 0x80u) | (t >> 7);
}

__device__ inline unsigned char f32_to_fp8_b(float v) {
#if __has_builtin(__builtin_amdgcn_cvt_pk_fp8_f32)
    return (unsigned char)(__builtin_amdgcn_cvt_pk_fp8_f32(v, v, 0, false) & 0xff);
#else
    return (unsigned char)f32_to_fp8_byte(v);
#endif
}

typedef int iv4 __attribute__((ext_vector_type(4)));

#define NPART 8
#define KB    32
#define NPP_MAX 12500
#define EB    2048   // edges per bucket block (8 per thread)

// ---------------- CSR build ----------------
// R16 lessons baked in:
//  - R3/R14: scatter-WRITE windows must be L2-sized (else ~16x writeback
//    amplification). count_part/fill2's partitioned LDS design guarantees it.
//  - R5: per-edge DEVICE atomics are memory-side (per-XCD L2s non-coherent):
//    1.6M atomics => ~56 MB coherence traffic + latency-bound kernel. Never
//    issue per-edge global atomics.
//  - R5 keeper: u32-packed pairs (dl<<srcb | src) halve pairs traffic.
// R6: bucket pass rebuilt around __ballot: per-slot, 8 ballots give every
// lane its partition rank and the wave counts in uniform registers -- zero
// per-edge atomics. 8 global atomics per block reserve segment space.

__global__ __launch_bounds__(256) void k_bucket_ballot(const int* __restrict__ src,
                                                       const int* __restrict__ dst,
                                                       int* __restrict__ cursor8,
                                                       unsigned* __restrict__ pairs,
                                                       int E, int npp, int capE,
                                                       int srcb) {
    __shared__ int sWcnt[4][NPART];
    __shared__ int sWoff[4][NPART];
    int tid = threadIdx.x;
    int wv = tid >> 6;
    int lane = tid & 63;
    int base_e = blockIdx.x * EB + tid * 8;
    int nv = min(8, E - base_e);
    if (nv < 0) nv = 0;
    int dv[8], sv[8];
    if (nv == 8) {
        *(iv4*)(dv + 0) = *(const iv4*)(dst + base_e + 0);
        *(iv4*)(dv + 4) = *(const iv4*)(dst + base_e + 4);
        *(iv4*)(sv + 0) = *(const iv4*)(src + base_e + 0);
        *(iv4*)(sv + 4) = *(const iv4*)(src + base_e + 4);
    } else {
        for (int k = 0; k < 8; ++k) {
            dv[k] = (k < nv) ? dst[base_e + k] : -1;
            sv[k] = (k < nv) ? src[base_e + k] : 0;
        }
    }
    unsigned long long below = (1ull << lane) - 1ull;
    int wb[NPART];
#pragma unroll
    for (int pp = 0; pp < NPART; ++pp) wb[pp] = 0;
    int pv[8], pos[8];
#pragma unroll
    for (int s = 0; s < 8; ++s) {
        int d = dv[s];
        int p = (d >= 0) ? (int)((unsigned)d / (unsigned)npp) : NPART;
        pv[s] = p;
        unsigned long long msel = 0;
        int base = 0;
#pragma unroll
        for (int pp = 0; pp < NPART; ++pp) {
            unsigned long long m = __ballot(p == pp);
            if (p == pp) { msel = m; base = wb[pp]; }
            wb[pp] += (int)__popcll(m);   // ballot result is wave-uniform
        }
        pos[s] = base + (int)__popcll(msel & below);
    }
    // wave totals -> LDS (static indexing to keep wb in registers)
    if (lane < NPART) {
        int v = 0;
#pragma unroll
        for (int pp = 0; pp < NPART; ++pp)
            if (lane == pp) v = wb[pp];
        sWcnt[wv][lane] = v;
    }
    __syncthreads();
    if (tid < NPART) {
        int c0 = sWcnt[0][tid], c1 = sWcnt[1][tid], c2 = sWcnt[2][tid], c3 = sWcnt[3][tid];
        int gb = atomicAdd(&cursor8[tid], c0 + c1 + c2 + c3);  // 8 atomics/block
        sWoff[0][tid] = gb;
        sWoff[1][tid] = gb + c0;
        sWoff[2][tid] = gb + c0 + c1;
        sWoff[3][tid] = gb + c0 + c1 + c2;
    }
    __syncthreads();
#pragma unroll
    for (int s = 0; s < 8; ++s) {
        int p = pv[s];
        if (p < NPART) {
            int off = sWoff[wv][p];
            pairs[(size_t)p * capE + off + pos[s]] =
                ((unsigned)(dv[s] - p * npp) << srcb) | (unsigned)sv[s];
        }
    }
}

__global__ __launch_bounds__(256) void k_count_part(const unsigned* __restrict__ pairs,
                                                    const int* __restrict__ cursor8,
                                                    int* __restrict__ cntarr,
                                                    int npp, int capE, int srcb) {
    __shared__ int h[NPP_MAX];
    int p = blockIdx.x & (NPART - 1);
    int b = blockIdx.x >> 3;
    for (int i = threadIdx.x; i < npp; i += 256) h[i] = 0;
    __syncthreads();
    int sz = cursor8[p];
    int chunk = (sz + KB - 1) / KB;
    int s0 = b * chunk;
    int s1 = min(sz, s0 + chunk);
    const unsigned* seg = pairs + (size_t)p * capE;
    for (int i = s0 + threadIdx.x; i < s1; i += 256)
        atomicAdd(&h[seg[i] >> srcb], 1);
    __syncthreads();
    size_t out = (size_t)(p * KB + b) * npp;
    for (int i = threadIdx.x; i < npp; i += 256) cntarr[out + i] = h[i];
}

// Fused: per-node degree (sum of 32 cntarr slices) -> dinv + block-local scan.
__global__ void k_indeg_scan(const int* __restrict__ cntarr,
                             float* __restrict__ dinv,
                             int* __restrict__ row_ptr,
                             int* __restrict__ partials, int n, int npp) {
    __shared__ int s[256];
    int t = threadIdx.x;
    int node0 = blockIdx.x * 1024 + t * 4;
    int v0 = 0, v1 = 0, v2 = 0, v3 = 0;
    if (((npp & 3) == 0) && (node0 + 3 < n) && (node0 / npp == (node0 + 3) / npp)) {
        int p = node0 / npp;
        int dl = node0 - p * npp;
        size_t base = (size_t)p * KB * npp + dl;
        for (int b = 0; b < KB; ++b) {
            iv4 c = *(const iv4*)(cntarr + base + (size_t)b * npp);
            v0 += c.x; v1 += c.y; v2 += c.z; v3 += c.w;
        }
    } else {
        for (int r = 0; r < 4; ++r) {
            int node = node0 + r;
            if (node < n) {
                int p = node / npp;
                int dl = node - p * npp;
                size_t base = (size_t)p * KB * npp + dl;
                int sum = 0;
                for (int b = 0; b < KB; ++b) sum += cntarr[base + (size_t)b * npp];
                if (r == 0) v0 = sum; else if (r == 1) v1 = sum;
                else if (r == 2) v2 = sum; else v3 = sum;
            }
        }
    }
    if (node0 + 0 < n) dinv[node0 + 0] = rsqrtf((float)v0 + 1.0f);
    if (node0 + 1 < n) dinv[node0 + 1] = rsqrtf((float)v1 + 1.0f);
    if (node0 + 2 < n) dinv[node0 + 2] = rsqrtf((float)v2 + 1.0f);
    if (node0 + 3 < n) dinv[node0 + 3] = rsqrtf((float)v3 + 1.0f);
    int sum = v0 + v1 + v2 + v3;
    s[t] = sum;
    __syncthreads();
    for (int off = 1; off < 256; off <<= 1) {
        int x = (t >= off) ? s[t - off] : 0;
        __syncthreads();
        s[t] += x;
        __syncthreads();
    }
    int excl = s[t] - sum;
    if ((node0 + 0) < n) row_ptr[node0 + 0] = excl;
    if ((node0 + 1) < n) row_ptr[node0 + 1] = excl + v0;
    if ((node0 + 2) < n) row_ptr[node0 + 2] = excl + v0 + v1;
    if ((node0 + 3) < n) row_ptr[node0 + 3] = excl + v0 + v1 + v2;
    if (t == 255) partials[blockIdx.x] = s[255];
}

__global__ void k_scan_partials(int* __restrict__ partials, int np) {
    __shared__ int s[256];
    int t = threadIdx.x;
    int v = (t < np) ? partials[t] : 0;
    s[t] = v;
    __syncthreads();
    for (int off = 1; off < 256; off <<= 1) {
        int x = (t >= off) ? s[t - off] : 0;
        __syncthreads();
        s[t] += x;
        __syncthreads();
    }
    if (t < np) partials[t] = s[t] - v;
}

// Fused: row_ptr fixup + per-slice base rewrite (cntarr becomes fill cursors).
__global__ void k_finalize_bases(int* __restrict__ row_ptr,
                                 const int* __restrict__ partials,
                                 int* __restrict__ cntarr, int n, int E, int npp) {
    int i = blockIdx.x * blockDim.x + threadIdx.x;
    if (i >= n) return;
    int rp = row_ptr[i] + partials[i >> 10];
    row_ptr[i] = rp;
    if (i == 0) row_ptr[n] = E;
    int p = (unsigned)i / (unsigned)npp;
    int dl = i - p * npp;
    size_t base = (size_t)p * KB * npp + dl;
    int run = rp;
    for (int b = 0; b < KB; ++b) {
        size_t idx = base + (size_t)b * npp;
        int c = cntarr[idx];
        cntarr[idx] = run;
        run += c;
    }
}

__global__ __launch_bounds__(256) void k_fill2(const unsigned* __restrict__ pairs,
                                               const int* __restrict__ cursor8,
                                               const int* __restrict__ cntarr,
                                               int* __restrict__ col,
                                               int npp, int capE, int srcb) {
    __shared__ int cur[NPP_MAX];
    int p = blockIdx.x & (NPART - 1);
    int b = blockIdx.x >> 3;
    size_t slice = (size_t)(p * KB + b) * npp;
    for (int i = threadIdx.x; i < npp; i += 256) cur[i] = cntarr[slice + i];
    __syncthreads();
    int sz = cursor8[p];
    int chunk = (sz + KB - 1) / KB;
    int s0 = b * chunk;
    int s1 = min(sz, s0 + chunk);
    const unsigned* seg = pairs + (size_t)p * capE;
    unsigned smask = (1u << srcb) - 1u;
    for (int i = s0 + threadIdx.x; i < s1; i += 256) {
        unsigned u = seg[i];
        int pos = atomicAdd(&cur[u >> srcb], 1);
        col[pos] = (int)(u & smask);
    }
}

// ---------------- MFMA GEMMs ----------------
typedef __attribute__((ext_vector_type(8))) short short8;
typedef __attribute__((ext_vector_type(4))) float f32x4;

union FragU {
    short8 s;
    uint4 u4;
    unsigned u[4];
};

__device__ inline void packW_body(const float* __restrict__ W, unsigned* __restrict__ Bp,
                                  int NOUT, int NT) {
    int nf = 4 * NT * 64;
    for (int fid = threadIdx.x; fid < nf; fid += 256) {
        int q = fid / (NT * 64);
        int rem = fid - q * NT * 64;
        int nt = rem >> 6;
        int lane = rem & 63;
        int k0 = q * 32 + (lane >> 4) * 8;
        int ncol = nt * 16 + (lane & 15);
        unsigned u[4];
        for (int h = 0; h < 4; ++h) {
            float a = W[(k0 + 2 * h) * NOUT + ncol];
            float b = W[(k0 + 2 * h + 1) * NOUT + ncol];
            u[h] = pack_bf16x2(a, b);
        }
        uint4 o = {u[0], u[1], u[2], u[3]};
        *(uint4*)(Bp + (size_t)fid * 4) = o;
    }
}

// both weight packs in one dispatch (block 0 -> W1, block 1 -> W2)
__global__ void k_packW2(const float* __restrict__ W1, unsigned* __restrict__ Bp1,
                         const float* __restrict__ W2, unsigned* __restrict__ Bp2) {
    if (blockIdx.x == 0) packW_body(W1, Bp1, 128, 8);
    else                 packW_body(W2, Bp2, 64, 4);
}

__global__ __launch_bounds__(256) void k_gemm128_mfma(const float* __restrict__ X,
                                                      const unsigned* __restrict__ Bp,
                                                      const float* __restrict__ dinv,
                                                      unsigned char* __restrict__ H8,
                                                      int n) {
    int w = threadIdx.x >> 6;
    int lane = threadIdx.x & 63;
    int quad = lane >> 4;
    int lrow = lane & 15;
    int row0 = blockIdx.x * 64 + w * 16;
    int rowA = min(row0 + lrow, n - 1);

    f32x4 acc[8];
    for (int nt = 0; nt < 8; ++nt) acc[nt] = (f32x4){0.f, 0.f, 0.f, 0.f};

    for (int q = 0; q < 4; ++q) {
        const float* xp = X + (size_t)rowA * 128 + q * 32 + quad * 8;
        float4 x0 = *(const float4*)xp;
        float4 x1 = *(const float4*)(xp + 4);
        FragU a;
        a.u[0] = pack_bf16x2(x0.x, x0.y);
        a.u[1] = pack_bf16x2(x0.z, x0.w);
        a.u[2] = pack_bf16x2(x1.x, x1.y);
        a.u[3] = pack_bf16x2(x1.z, x1.w);
        for (int nt = 0; nt < 8; ++nt) {
            FragU b;
            b.u4 = *(const uint4*)(Bp + ((size_t)(q * 8 + nt) * 64 + lane) * 4);
            acc[nt] = __builtin_amdgcn_mfma_f32_16x16x32_bf16(a.s, b.s, acc[nt], 0, 0, 0);
        }
    }

    int rbase = row0 + quad * 4;
    float dv[4];
    if (rbase + 3 < n) {
        float4 d4 = *(const float4*)(dinv + rbase);
        dv[0] = d4.x; dv[1] = d4.y; dv[2] = d4.z; dv[3] = d4.w;
    } else {
        for (int r = 0; r < 4; ++r) dv[r] = dinv[min(rbase + r, n - 1)];
    }
    for (int nt = 0; nt < 8; ++nt) {
        for (int r = 0; r < 4; ++r) {
            int row = rbase + r;
            if (row < n)
                H8[(size_t)row * 128 + nt * 16 + lrow] = f32_to_fp8_b(dv[r] * acc[nt][r]);
        }
    }
}

__global__ __launch_bounds__(256) void k_gemm64_mfma(const unsigned* __restrict__ Xb,
                                                     const unsigned* __restrict__ Bp,
                                                     const float* __restrict__ dinv,
                                                     unsigned short* __restrict__ H16,
                                                     int n) {
    int w = threadIdx.x >> 6;
    int lane = threadIdx.x & 63;
    int quad = lane >> 4;
    int lrow = lane & 15;
    int row0 = blockIdx.x * 64 + w * 16;
    int rowA = min(row0 + lrow, n - 1);

    f32x4 acc[4];
    for (int nt = 0; nt < 4; ++nt) acc[nt] = (f32x4){0.f, 0.f, 0.f, 0.f};

    for (int q = 0; q < 4; ++q) {
        FragU a;
        a.u4 = *(const uint4*)(Xb + (size_t)rowA * 64 + q * 16 + quad * 4);
        for (int nt = 0; nt < 4; ++nt) {
            FragU b;
            b.u4 = *(const uint4*)(Bp + ((size_t)(q * 4 + nt) * 64 + lane) * 4);
            acc[nt] = __builtin_amdgcn_mfma_f32_16x16x32_bf16(a.s, b.s, acc[nt], 0, 0, 0);
        }
    }

    int rbase = row0 + quad * 4;
    float dv[4];
    if (rbase + 3 < n) {
        float4 d4 = *(const float4*)(dinv + rbase);
        dv[0] = d4.x; dv[1] = d4.y; dv[2] = d4.z; dv[3] = d4.w;
    } else {
        for (int r = 0; r < 4; ++r) dv[r] = dinv[min(rbase + r, n - 1)];
    }
    for (int nt = 0; nt < 4; ++nt) {
        for (int r = 0; r < 4; ++r) {
            int row = rbase + r;
            if (row < n)
                H16[(size_t)row * 64 + nt * 16 + lrow] = bf16_rne(dv[r] * acc[nt][r]);
        }
    }
}

// ---------------- Pull-mode aggregation: quarter-wave PER NODE ----------------
// R13-proven structure: each 16-lane quarter owns ONE node; lane l owns bytes
// 8l..8l+7 of the node's 128 B feature row. No cross-lane reduce in layer 1;
// col indices are quarter-uniform scalar loads; 8-edge unroll keeps 8 loads
// in flight per lane.

// Layer 1: hs rows = 16 uint2 (128 fp8). Lane owns fp8 cols 8l..8l+7.
__global__ __launch_bounds__(256) void k_agg_relu(const unsigned* __restrict__ hs,
                                                  const float* __restrict__ dinv,
                                                  const int* __restrict__ row_ptr,
                                                  const int* __restrict__ col,
                                                  const float* __restrict__ bias,
                                                  unsigned* __restrict__ out, int n) {
    int node = blockIdx.x * 16 + (threadIdx.x >> 4);
    if (node >= n) return;
    int l = threadIdx.x & 15;
    const uint2* hrow = (const uint2*)hs;
    fv2 a0 = {0.f, 0.f}, a1 = {0.f, 0.f}, a2 = {0.f, 0.f}, a3 = {0.f, 0.f};
    {   // self term
        uint2 u = hrow[(size_t)node * 16 + l];
        a0 += fp8_fv2<false>(u.x); a1 += fp8_fv2<true>(u.x);
        a2 += fp8_fv2<false>(u.y); a3 += fp8_fv2<true>(u.y);
    }
    int k = row_ptr[node], p1 = row_ptr[node + 1];
    for (; k + 8 <= p1; k += 8) {  // 8 edges/quarter, 8 loads in flight/lane
        int cA = col[k + 0], cB = col[k + 1], cC = col[k + 2], cD = col[k + 3];
        int cE = col[k + 4], cF = col[k + 5], cG = col[k + 6], cH = col[k + 7];
        uint2 uA = hrow[(size_t)cA * 16 + l];
        uint2 uB = hrow[(size_t)cB * 16 + l];
        uint2 uC = hrow[(size_t)cC * 16 + l];
        uint2 uD = hrow[(size_t)cD * 16 + l];
        uint2 uE = hrow[(size_t)cE * 16 + l];
        uint2 uF = hrow[(size_t)cF * 16 + l];
        uint2 uG = hrow[(size_t)cG * 16 + l];
        uint2 uH = hrow[(size_t)cH * 16 + l];
        a0 += fp8_fv2<false>(uA.x); a1 += fp8_fv2<true>(uA.x);
        a2 += fp8_fv2<false>(uA.y); a3 += fp8_fv2<true>(uA.y);
        a0 += fp8_fv2<false>(uB.x); a1 += fp8_fv2<true>(uB.x);
        a2 += fp8_fv2<false>(uB.y); a3 += fp8_fv2<true>(uB.y);
        a0 += fp8_fv2<false>(uC.x); a1 += fp8_fv2<true>(uC.x);
        a2 += fp8_fv2<false>(uC.y); a3 += fp8_fv2<true>(uC.y);
        a0 += fp8_fv2<false>(uD.x); a1 += fp8_fv2<true>(uD.x);
        a2 += fp8_fv2<false>(uD.y); a3 += fp8_fv2<true>(uD.y);
        a0 += fp8_fv2<false>(uE.x); a1 += fp8_fv2<true>(uE.x);
        a2 += fp8_fv2<false>(uE.y); a3 += fp8_fv2<true>(uE.y);
        a0 += fp8_fv2<false>(uF.x); a1 += fp8_fv2<true>(uF.x);
        a2 += fp8_fv2<false>(uF.y); a3 += fp8_fv2<true>(uF.y);
        a0 += fp8_fv2<false>(uG.x); a1 += fp8_fv2<true>(uG.x);
        a2 += fp8_fv2<false>(uG.y); a3 += fp8_fv2<true>(uG.y);
        a0 += fp8_fv2<false>(uH.x); a1 += fp8_fv2<true>(uH.x);
        a2 += fp8_fv2<false>(uH.y); a3 += fp8_fv2<true>(uH.y);
    }
    for (; k + 4 <= p1; k += 4) {
        int cA = col[k + 0], cB = col[k + 1], cC = col[k + 2], cD = col[k + 3];
        uint2 uA = hrow[(size_t)cA * 16 + l];
        uint2 uB = hrow[(size_t)cB * 16 + l];
        uint2 uC = hrow[(size_t)cC * 16 + l];
        uint2 uD = hrow[(size_t)cD * 16 + l];
        a0 += fp8_fv2<false>(uA.x); a1 += fp8_fv2<true>(uA.x);
        a2 += fp8_fv2<false>(uA.y); a3 += fp8_fv2<true>(uA.y);
        a0 += fp8_fv2<false>(uB.x); a1 += fp8_fv2<true>(uB.x);
        a2 += fp8_fv2<false>(uB.y); a3 += fp8_fv2<true>(uB.y);
        a0 += fp8_fv2<false>(uC.x); a1 += fp8_fv2<true>(uC.x);
        a2 += fp8_fv2<false>(uC.y); a3 += fp8_fv2<true>(uC.y);
        a0 += fp8_fv2<false>(uD.x); a1 += fp8_fv2<true>(uD.x);
        a2 += fp8_fv2<false>(uD.y); a3 += fp8_fv2<true>(uD.y);
    }
    for (; k < p1; ++k) {
        int j = col[k];
        uint2 u = hrow[(size_t)j * 16 + l];
        a0 += fp8_fv2<false>(u.x); a1 += fp8_fv2<true>(u.x);
        a2 += fp8_fv2<false>(u.y); a3 += fp8_fv2<true>(u.y);
    }
    // epilogue: every lane finalizes its own 8 columns (4 nodes per wave)
    float di = dinv[node];
    float4 b4a = *(const float4*)(bias + 8 * l);
    float4 b4b = *(const float4*)(bias + 8 * l + 4);
    float v0 = fmaf(di, a0.x, b4a.x);
    float v1 = fmaf(di, a0.y, b4a.y);
    float v2 = fmaf(di, a1.x, b4a.z);
    float v3 = fmaf(di, a1.y, b4a.w);
    float v4 = fmaf(di, a2.x, b4b.x);
    float v5 = fmaf(di, a2.y, b4b.y);
    float v6 = fmaf(di, a3.x, b4b.z);
    float v7 = fmaf(di, a3.y, b4b.w);
    v0 = v0 > 0.f ? v0 : 0.f;
    v1 = v1 > 0.f ? v1 : 0.f;
    v2 = v2 > 0.f ? v2 : 0.f;
    v3 = v3 > 0.f ? v3 : 0.f;
    v4 = v4 > 0.f ? v4 : 0.f;
    v5 = v5 > 0.f ? v5 : 0.f;
    v6 = v6 > 0.f ? v6 : 0.f;
    v7 = v7 > 0.f ? v7 : 0.f;
    uint4 o = {pack_bf16x2(v0, v1), pack_bf16x2(v2, v3),
               pack_bf16x2(v4, v5), pack_bf16x2(v6, v7)};
    *(uint4*)(out + (size_t)node * 64 + 4 * l) = o;
}

// Layer 2: hs rows = 16 uint2 (64 bf16). Lane owns bf16 cols 4l..4l+3.
// Fused log_softmax: 16-lane reduce (xor offsets 1..8 stay inside the quarter).
__global__ __launch_bounds__(256) void k_agg_lsm(const unsigned* __restrict__ hs,
                                                 const float* __restrict__ dinv,
                                                 const int* __restrict__ row_ptr,
                                                 const int* __restrict__ col,
                                                 const float* __restrict__ bias,
                                                 float* __restrict__ out, int n) {
    int node = blockIdx.x * 16 + (threadIdx.x >> 4);
    if (node >= n) return;
    int l = threadIdx.x & 15;
    const uint2* hrow = (const uint2*)hs;
    fv2 aX = {0.f, 0.f}, aY = {0.f, 0.f};
    {   // self term
        uint2 u = hrow[(size_t)node * 16 + l];
        aX += bfpair(u.x);
        aY += bfpair(u.y);
    }
    int k = row_ptr[node], p1 = row_ptr[node + 1];
    for (; k + 8 <= p1; k += 8) {
        int cA = col[k + 0], cB = col[k + 1], cC = col[k + 2], cD = col[k + 3];
        int cE = col[k + 4], cF = col[k + 5], cG = col[k + 6], cH = col[k + 7];
        uint2 uA = hrow[(size_t)cA * 16 + l];
        uint2 uB = hrow[(size_t)cB * 16 + l];
        uint2 uC = hrow[(size_t)cC * 16 + l];
        uint2 uD = hrow[(size_t)cD * 16 + l];
        uint2 uE = hrow[(size_t)cE * 16 + l];
        uint2 uF = hrow[(size_t)cF * 16 + l];
        uint2 uG = hrow[(size_t)cG * 16 + l];
        uint2 uH = hrow[(size_t)cH * 16 + l];
        aX += bfpair(uA.x); aY += bfpair(uA.y);
        aX += bfpair(uB.x); aY += bfpair(uB.y);
        aX += bfpair(uC.x); aY += bfpair(uC.y);
        aX += bfpair(uD.x); aY += bfpair(uD.y);
        aX += bfpair(uE.x); aY += bfpair(uE.y);
        aX += bfpair(uF.x); aY += bfpair(uF.y);
        aX += bfpair(uG.x); aY += bfpair(uG.y);
        aX += bfpair(uH.x); aY += bfpair(uH.y);
    }
    for (; k + 4 <= p1; k += 4) {
        int cA = col[k + 0], cB = col[k + 1], cC = col[k + 2], cD = col[k + 3];
        uint2 uA = hrow[(size_t)cA * 16 + l];
        uint2 uB = hrow[(size_t)cB * 16 + l];
        uint2 uC = hrow[(size_t)cC * 16 + l];
        uint2 uD = hrow[(size_t)cD * 16 + l];
        aX += bfpair(uA.x); aY += bfpair(uA.y);
        aX += bfpair(uB.x); aY += bfpair(uB.y);
        aX += bfpair(uC.x); aY += bfpair(uC.y);
        aX += bfpair(uD.x); aY += bfpair(uD.y);
    }
    for (; k < p1; ++k) {
        int j = col[k];
        uint2 u = hrow[(size_t)j * 16 + l];
        aX += bfpair(u.x); aY += bfpair(u.y);
    }
    float di = dinv[node];
    float4 b4 = *(const float4*)(bias + 4 * l);
    float v0 = fmaf(di, aX.x, b4.x);
    float v1 = fmaf(di, aX.y, b4.y);
    float v2 = fmaf(di, aY.x, b4.z);
    float v3 = fmaf(di, aY.y, b4.w);
    float m = fmaxf(fmaxf(v0, v1), fmaxf(v2, v3));
    for (int off = 8; off; off >>= 1) m = fmaxf(m, __shfl_xor(m, off));
    float s = __expf(v0 - m) + __expf(v1 - m) + __expf(v2 - m) + __expf(v3 - m);
    for (int off = 8; off; off >>= 1) s += __shfl_xor(s, off);
    float ls = __logf(s);
    float4 o = {v0 - m - ls, v1 - m - ls, v2 - m - ls, v3 - m - ls};
    *(float4*)(out + (size_t)node * 64 + 4 * l) = o;
}

// ---------------- launcher ----------------

extern "C" void kernel_launch(void* const* d_in, const int* in_sizes, int n_in,
                              void* d_out, int out_size, void* d_ws, size_t ws_size,
                              hipStream_t stream) {
    const float* x  = (const float*)d_in[0];
    const int*   ei = (const int*)d_in[1];
    const float* W1 = (const float*)d_in[2];
    const float* b1 = (const float*)d_in[3];
    const float* W2 = (const float*)d_in[4];
    const float* b2 = (const float*)d_in[5];
    float* out = (float*)d_out;

    const int N = in_sizes[0] / 128;   // 100000
    const int E = in_sizes[1] / 2;     // 1600000
    const int* src = ei;
    const int* dst = ei + E;
    const int npp = (N + NPART - 1) / NPART;           // 12500
    const int capE = (E + NPART - 1) / NPART + 32768;  // segment capacity + slack
    int srcb = 1;
    while ((1 << srcb) < N) ++srcb;                    // 17 for N=100000

    char* w = (char*)d_ws;
    size_t off = 0;
    auto alloc = [&](size_t bytes) -> void* {
        void* p = w + off;
        off += (bytes + 255) & ~(size_t)255;
        return p;
    };
    int*      row_ptr  = (int*)alloc((size_t)(N + 1) * 4);
    int*      colarr   = (int*)alloc((size_t)E * 4);
    int*      partials = (int*)alloc(256 * 4);
    int*      cursor8  = (int*)alloc(8 * 4);
    float*    dinv     = (float*)alloc((size_t)N * 4);
    unsigned* h1f8     = (unsigned*)alloc((size_t)N * 32 * 4);  // fp8 X@W1 scaled
    unsigned* a1b      = (unsigned*)alloc((size_t)N * 64 * 4);  // bf16 relu out
    unsigned* h2b      = (unsigned*)alloc((size_t)N * 32 * 4);  // bf16 a1@W2 scaled
    unsigned* Bp1      = (unsigned*)alloc(4 * 8 * 64 * 16);     // W1 frag stream 32KB
    unsigned* Bp2      = (unsigned*)alloc(4 * 4 * 64 * 16);     // W2 frag stream 16KB
    // pairs (7.5 MB) + cntarr (12.8 MB) alias a1b (25.6 MB), dead before agg_relu
    unsigned* pairsU   = (unsigned*)a1b;
    int*      cntarr   = (int*)((char*)a1b + (size_t)NPART * capE * 4);
    (void)ws_size; (void)n_in; (void)out_size;

    int nscan = (N + 1023) / 1024;
    int nbb = (E + EB - 1) / EB;       // 782 bucket blocks
    int ngemm = (N + 63) / 64;

    hipMemsetAsync(cursor8, 0, 8 * 4, stream);
    k_packW2<<<2, 256, 0, stream>>>(W1, Bp1, W2, Bp2);
    k_bucket_ballot<<<nbb, 256, 0, stream>>>(src, dst, cursor8, pairsU,
                                             E, npp, capE, srcb);
    k_count_part<<<NPART * KB, 256, 0, stream>>>(pairsU, cursor8, cntarr,
                                                 npp, capE, srcb);
    k_indeg_scan<<<nscan, 256, 0, stream>>>(cntarr, dinv, row_ptr, partials, N, npp);
    k_scan_partials<<<1, 256, 0, stream>>>(partials, nscan);
    k_finalize_bases<<<(N + 255) / 256, 256, 0, stream>>>(row_ptr, partials, cntarr,
                                                          N, E, npp);
    k_fill2<<<NPART * KB, 256, 0, stream>>>(pairsU, cursor8, cntarr, colarr,
                                            npp, capE, srcb);

    k_gemm128_mfma<<<ngemm, 256, 0, stream>>>(x, Bp1, dinv, (unsigned char*)h1f8, N);
    k_agg_relu<<<(N + 15) / 16, 256, 0, stream>>>(h1f8, dinv, row_ptr, colarr, b1, a1b, N);
    k_gemm64_mfma<<<ngemm, 256, 0, stream>>>(a1b, Bp2, dinv, (unsigned short*)h2b, N);
    k_agg_lsm<<<(N + 15) / 16, 256, 0, stream>>>(h2b, dinv, row_ptr, colarr, b2, out, N);
}